// Round 4
// baseline (221.866 us; speedup 1.0000x reference)
//
#include <hip/hip_runtime.h>
#include <math.h>

#define B_  2
#define S_  2048
#define H_  768
#define NH_ 12
#define HD_ 64
#define M_  (B_ * S_)    // 4096
#define BH_ (B_ * NH_)   // 24

typedef __attribute__((ext_vector_type(8))) short bf16x8;
typedef __attribute__((ext_vector_type(4))) short bf16x4;
typedef __attribute__((ext_vector_type(4))) float f32x4;

static __device__ __forceinline__ short f2bf(float x) {
  unsigned u = __builtin_bit_cast(unsigned, x);
  u += 0x7FFFu + ((u >> 16) & 1u);   // RNE
  return (short)(u >> 16);
}

#define MFMA16(a, b, c) __builtin_amdgcn_mfma_f32_16x16x32_bf16((a), (b), (c), 0, 0, 0)

// ---------------------------------------------------------------------------
// Kernel 0: X fp32 -> bf16, elementwise. grid 1536, block 256, 8 el/thread.
// ---------------------------------------------------------------------------
__global__ __launch_bounds__(256) void xprep_kernel(const float* __restrict__ X,
                                                    short* __restrict__ Xb) {
  const int i = (blockIdx.x * 256 + threadIdx.x) * 8;
  const float4 a = *(const float4*)&X[i];
  const float4 b = *(const float4*)&X[i + 4];
  short tmp[8] = {f2bf(a.x), f2bf(a.y), f2bf(a.z), f2bf(a.w),
                  f2bf(b.x), f2bf(b.y), f2bf(b.z), f2bf(b.w)};
  *(bf16x8*)&Xb[i] = *(const bf16x8*)tmp;
}

// ---------------------------------------------------------------------------
// Kernel 1: W[k][n] fp32 -> Wt[mat][n][k] bf16 (transpose + convert).
// grid (12,12,3) block 256.
// ---------------------------------------------------------------------------
__global__ __launch_bounds__(256) void wprep_kernel(
    const float* __restrict__ Wq, const float* __restrict__ Wk,
    const float* __restrict__ Wv, short* __restrict__ Wt) {
  const int mat = blockIdx.z;
  const float* W = (mat == 0) ? Wq : (mat == 1 ? Wk : Wv);
  const int bk = blockIdx.x * 64, bn = blockIdx.y * 64;
  __shared__ float T[64][68];  // [k][n]
  const int t = threadIdx.x;
  {
    const int n = t & 63, kq = t >> 6;
#pragma unroll
    for (int u = 0; u < 16; ++u) {
      const int k = kq * 16 + u;
      T[k][n] = W[(size_t)(bk + k) * H_ + bn + n];
    }
  }
  __syncthreads();
  {
    const int n = t >> 2, c0 = (t & 3) * 16;
    short tmp[16];
#pragma unroll
    for (int j = 0; j < 16; ++j) tmp[j] = f2bf(T[c0 + j][n]);
    short* dst = Wt + ((size_t)mat * H_ + bn + n) * H_ + bk + c0;
    *(bf16x8*)dst = *(const bf16x8*)tmp;
    *(bf16x8*)(dst + 8) = *(const bf16x8*)(tmp + 8);
  }
}

// ---------------------------------------------------------------------------
// Kernel 2: QKV projection, bf16 MFMA. C = Xb @ Wt^T + b; Q pre-scaled 1/8.
// Output bf16 [bh][s][d]. grid (32,12,3) block 256 (4 waves, 2x2).
// ---------------------------------------------------------------------------
__global__ __launch_bounds__(256) void qkv_gemm_kernel(
    const short* __restrict__ Xb, const short* __restrict__ Wt,
    const float* __restrict__ bq, const float* __restrict__ bk,
    const float* __restrict__ bv, short* __restrict__ QKV) {
  const int mat = blockIdx.z;
  const float* bias = (mat == 0) ? bq : (mat == 1 ? bk : bv);
  const float qscale = (mat == 0) ? 0.125f : 1.0f;
  const short* Wm = Wt + (size_t)mat * H_ * H_;
  short* out = QKV + (size_t)mat * M_ * HD_ * NH_;

  __shared__ short Xs[128][40];  // [m][k] bf16, pitch 80B
  __shared__ short Ws[64][40];   // [n][k] bf16

  const int t = threadIdx.x;
  const int w = t >> 6, l = t & 63, c = l & 15, g = l >> 4;
  const int wm = w >> 1, wn = w & 1;
  const int bm = blockIdx.x * 128, bn = blockIdx.y * 64;

  const f32x4 fz = {0.f, 0.f, 0.f, 0.f};
  f32x4 acc[4][2];
#pragma unroll
  for (int i = 0; i < 4; ++i) { acc[i][0] = fz; acc[i][1] = fz; }

  for (int k0 = 0; k0 < H_; k0 += 32) {
    {
#pragma unroll
      for (int u = 0; u < 2; ++u) {
        const int i = u * 256 + t;
        const int row = i >> 2, kc = (i & 3) * 8;
        *(bf16x8*)&Xs[row][kc] =
            *(const bf16x8*)&Xb[(size_t)(bm + row) * H_ + k0 + kc];
      }
      const int n = t >> 2, kc = (t & 3) * 8;
      *(bf16x8*)&Ws[n][kc] = *(const bf16x8*)&Wm[(size_t)(bn + n) * H_ + k0 + kc];
    }
    __syncthreads();
    bf16x8 af[4], bfr[2];
#pragma unroll
    for (int mt = 0; mt < 4; ++mt)
      af[mt] = *(const bf16x8*)&Xs[wm * 64 + mt * 16 + c][g * 8];
#pragma unroll
    for (int nt = 0; nt < 2; ++nt)
      bfr[nt] = *(const bf16x8*)&Ws[wn * 32 + nt * 16 + c][g * 8];
#pragma unroll
    for (int mt = 0; mt < 4; ++mt)
#pragma unroll
      for (int nt = 0; nt < 2; ++nt)
        acc[mt][nt] = MFMA16(af[mt], bfr[nt], acc[mt][nt]);
    __syncthreads();
  }

  const int h = blockIdx.y;  // head (BN == HD)
#pragma unroll
  for (int nt = 0; nt < 2; ++nt) {
    const int col = wn * 32 + nt * 16 + c;
    const float bsc = bias[bn + col] * qscale;
#pragma unroll
    for (int mt = 0; mt < 4; ++mt) {
#pragma unroll
      for (int r = 0; r < 4; ++r) {
        const int row = bm + wm * 64 + mt * 16 + g * 4 + r;
        const int bb = row >> 11, ss = row & (S_ - 1);
        out[((size_t)(bb * NH_ + h) * S_ + ss) * HD_ + col] =
            f2bf(acc[mt][nt][r] * qscale + bsc);
      }
    }
  }
}

// ---------------------------------------------------------------------------
// Kernel 3: V [bh][s][d] -> Vt [bh][d][s] (bf16). grid (32,24) block 256.
// ---------------------------------------------------------------------------
__global__ __launch_bounds__(256) void vtrans_kernel(const short* __restrict__ V,
                                                     short* __restrict__ Vt) {
  const int bh = blockIdx.y, s0 = blockIdx.x * 64;
  __shared__ short T[64][72];  // [s][d]
  const int t = threadIdx.x;
  {
    const short* src = V + ((size_t)bh * S_ + s0) * HD_;
#pragma unroll
    for (int u = 0; u < 2; ++u) {
      const int i = u * 256 + t;
      *(bf16x8*)&T[i >> 3][(i & 7) * 8] = *(const bf16x8*)&src[i * 8];
    }
  }
  __syncthreads();
  {
    const int d = t >> 2, sc = (t & 3) * 16;
    short tmp[16];
#pragma unroll
    for (int j = 0; j < 16; ++j) tmp[j] = T[sc + j][d];
    short* dst = Vt + ((size_t)bh * HD_ + d) * S_ + s0 + sc;
    *(bf16x8*)dst = *(const bf16x8*)tmp;
    *(bf16x8*)(dst + 8) = *(const bf16x8*)(tmp + 8);
  }
}

// ---------------------------------------------------------------------------
// Kernel 4: flash attention, bf16 MFMA, fp32 softmax/accum.
// Block = (qt 64 rows, bh). 4 waves x 16 q-rows each. KV tile 64.
// grid (32,24) block 256.
// ---------------------------------------------------------------------------
__global__ __launch_bounds__(256) void attn_kernel(const short* __restrict__ Q,
                                                   const short* __restrict__ K,
                                                   const short* __restrict__ Vt,
                                                   float* __restrict__ out) {
  __shared__ short Qs[64][72], Ks[64][72], Vs[64][72];  // pitch 144B
  __shared__ short Ps[4][16][72];                        // per-wave P tile

  const int t = threadIdx.x;
  const int w = t >> 6, l = t & 63, c = l & 15, g = l >> 4;
  const int qt = blockIdx.x, bh = blockIdx.y;
  const size_t base = (size_t)bh * S_ * HD_;

  {  // stage Q (contiguous 8KB)
    const short* src = Q + base + (size_t)qt * 64 * HD_;
#pragma unroll
    for (int u = 0; u < 2; ++u) {
      const int i = u * 256 + t;
      *(bf16x8*)&Qs[i >> 3][(i & 7) * 8] = *(const bf16x8*)&src[i * 8];
    }
  }

  const f32x4 fz = {0.f, 0.f, 0.f, 0.f};
  f32x4 ctx[4];
  float m_i[4], l_i[4];
#pragma unroll
  for (int r = 0; r < 4; ++r) { m_i[r] = -INFINITY; l_i[r] = 0.f; ctx[r] = fz; }

  for (int kt = 0; kt < S_ / 64; ++kt) {
    {  // stage K tile (contiguous) + Vt tile (row chunks)
      const short* ksrc = K + base + (size_t)kt * 64 * HD_;
#pragma unroll
      for (int u = 0; u < 2; ++u) {
        const int i = u * 256 + t;
        *(bf16x8*)&Ks[i >> 3][(i & 7) * 8] = *(const bf16x8*)&ksrc[i * 8];
      }
      const short* vsrc = Vt + (size_t)bh * HD_ * S_ + kt * 64;
      const int d = t >> 2;
#pragma unroll
      for (int u = 0; u < 2; ++u) {
        const int ch = ((t & 3) + u * 4) * 8;
        *(bf16x8*)&Vs[d][ch] = *(const bf16x8*)&vsrc[(size_t)d * S_ + ch];
      }
    }
    __syncthreads();

    // scores: A-frag = Q rows, B-frag = K rows (both k-contig)
    f32x4 sc[4] = {fz, fz, fz, fz};
    bf16x8 qa[2];
#pragma unroll
    for (int ks = 0; ks < 2; ++ks)
      qa[ks] = *(const bf16x8*)&Qs[w * 16 + c][ks * 32 + g * 8];
#pragma unroll
    for (int nt = 0; nt < 4; ++nt)
#pragma unroll
      for (int ks = 0; ks < 2; ++ks) {
        const bf16x8 kb = *(const bf16x8*)&Ks[nt * 16 + c][ks * 32 + g * 8];
        sc[nt] = MFMA16(qa[ks], kb, sc[nt]);
      }

    // online softmax; q-row = w*16 + g*4 + r, spread over 16 lanes (c) x 4 frags
#pragma unroll
    for (int r = 0; r < 4; ++r) {
      float mx = fmaxf(fmaxf(sc[0][r], sc[1][r]), fmaxf(sc[2][r], sc[3][r]));
#pragma unroll
      for (int off = 1; off <= 8; off <<= 1) mx = fmaxf(mx, __shfl_xor(mx, off));
      const float mnew = fmaxf(m_i[r], mx);
      const float rs = __expf(m_i[r] - mnew);
      const float p0 = __expf(sc[0][r] - mnew), p1 = __expf(sc[1][r] - mnew);
      const float p2 = __expf(sc[2][r] - mnew), p3 = __expf(sc[3][r] - mnew);
      float ps = p0 + p1 + p2 + p3;
#pragma unroll
      for (int off = 1; off <= 8; off <<= 1) ps += __shfl_xor(ps, off);
      l_i[r] = l_i[r] * rs + ps;
      m_i[r] = mnew;
#pragma unroll
      for (int dt = 0; dt < 4; ++dt) ctx[dt][r] *= rs;
      Ps[w][g * 4 + r][c]      = f2bf(p0);
      Ps[w][g * 4 + r][16 + c] = f2bf(p1);
      Ps[w][g * 4 + r][32 + c] = f2bf(p2);
      Ps[w][g * 4 + r][48 + c] = f2bf(p3);
    }

    // PV: A-frag = P rows (wave-private, no barrier), B-frag = Vt rows
    bf16x8 pa[2];
#pragma unroll
    for (int kb = 0; kb < 2; ++kb)
      pa[kb] = *(const bf16x8*)&Ps[w][c][kb * 32 + g * 8];
#pragma unroll
    for (int dt = 0; dt < 4; ++dt)
#pragma unroll
      for (int kb = 0; kb < 2; ++kb) {
        const bf16x8 vb = *(const bf16x8*)&Vs[dt * 16 + c][kb * 32 + g * 8];
        ctx[dt] = MFMA16(pa[kb], vb, ctx[dt]);
      }
    __syncthreads();  // all waves done with Ks/Vs before restage
  }

  const int bb = bh / NH_, hh = bh % NH_;
#pragma unroll
  for (int r = 0; r < 4; ++r) {
    const float inv = 1.f / l_i[r];
    const int s = qt * 64 + w * 16 + g * 4 + r;
#pragma unroll
    for (int dt = 0; dt < 4; ++dt)
      out[((size_t)bb * S_ + s) * H_ + hh * HD_ + dt * 16 + c] = ctx[dt][r] * inv;
  }
}

// ---------------------------------------------------------------------------
extern "C" void kernel_launch(void* const* d_in, const int* in_sizes, int n_in,
                              void* d_out, int out_size, void* d_ws, size_t ws_size,
                              hipStream_t stream) {
  const float* X  = (const float*)d_in[0];
  const float* Wq = (const float*)d_in[1];
  const float* bq = (const float*)d_in[2];
  const float* Wk = (const float*)d_in[3];
  const float* bk = (const float*)d_in[4];
  const float* Wv = (const float*)d_in[5];
  const float* bv = (const float*)d_in[6];
  float* out = (float*)d_out;

  // ws layout (bf16 el): QKV[3][24][2048][64] | Vt[24][64][2048] | Wt[3][768][768] | Xb[4096][768]
  short* ws  = (short*)d_ws;
  short* QKV = ws;                                       // 3 * 3,145,728 el
  short* Vt  = ws + (size_t)3 * M_ * H_;                 // 3,145,728 el
  short* Wt  = ws + (size_t)4 * M_ * H_;                 // 1,769,472 el
  short* Xb  = Wt + (size_t)3 * H_ * H_;                 // 3,145,728 el (~35 MB total)
  const short* V = QKV + (size_t)2 * M_ * H_;

  xprep_kernel<<<dim3((M_ * H_) / (256 * 8)), 256, 0, stream>>>(X, Xb);
  wprep_kernel<<<dim3(12, 12, 3), 256, 0, stream>>>(Wq, Wk, Wv, Wt);
  qkv_gemm_kernel<<<dim3(M_ / 128, H_ / 64, 3), 256, 0, stream>>>(Xb, Wt, bq, bk, bv, QKV);
  vtrans_kernel<<<dim3(S_ / 64, BH_), 256, 0, stream>>>(V, Vt);
  attn_kernel<<<dim3(S_ / 64, BH_), 256, 0, stream>>>(QKV, QKV + (size_t)M_ * H_, Vt, out);
}

// Round 6
// 207.473 us; speedup vs baseline: 1.0694x; 1.0694x over previous
//
#include <hip/hip_runtime.h>
#include <math.h>

#define B_  2
#define S_  2048
#define H_  768
#define NH_ 12
#define HD_ 64
#define M_  (B_ * S_)    // 4096
#define BH_ (B_ * NH_)   // 24
#define LOG2E_ 1.44269504088896f

typedef __attribute__((ext_vector_type(8))) short bf16x8;
typedef __attribute__((ext_vector_type(4))) short bf16x4;
typedef __attribute__((ext_vector_type(4))) float f32x4;

static __device__ __forceinline__ short f2bf(float x) {
  unsigned u = __builtin_bit_cast(unsigned, x);
  u += 0x7FFFu + ((u >> 16) & 1u);   // RNE
  return (short)(u >> 16);
}

#define MFMA16(a, b, c) __builtin_amdgcn_mfma_f32_16x16x32_bf16((a), (b), (c), 0, 0, 0)

// ---------------------------------------------------------------------------
// Kernel 0: X fp32 -> bf16. grid 1536, block 256, 8 el/thread.
// ---------------------------------------------------------------------------
__global__ __launch_bounds__(256) void xprep_kernel(const float* __restrict__ X,
                                                    short* __restrict__ Xb) {
  const int i = (blockIdx.x * 256 + threadIdx.x) * 8;
  const float4 a = *(const float4*)&X[i];
  const float4 b = *(const float4*)&X[i + 4];
  short tmp[8] = {f2bf(a.x), f2bf(a.y), f2bf(a.z), f2bf(a.w),
                  f2bf(b.x), f2bf(b.y), f2bf(b.z), f2bf(b.w)};
  *(bf16x8*)&Xb[i] = *(const bf16x8*)tmp;
}

// ---------------------------------------------------------------------------
// Kernel 1: W[k][n] fp32 -> Wt[mat][n][k] bf16. grid (12,12,3) block 256.
// ---------------------------------------------------------------------------
__global__ __launch_bounds__(256) void wprep_kernel(
    const float* __restrict__ Wq, const float* __restrict__ Wk,
    const float* __restrict__ Wv, short* __restrict__ Wt) {
  const int mat = blockIdx.z;
  const float* W = (mat == 0) ? Wq : (mat == 1 ? Wk : Wv);
  const int bk = blockIdx.x * 64, bn = blockIdx.y * 64;
  __shared__ float T[64][68];
  const int t = threadIdx.x;
  {
    const int n = t & 63, kq = t >> 6;
#pragma unroll
    for (int u = 0; u < 16; ++u) {
      const int k = kq * 16 + u;
      T[k][n] = W[(size_t)(bk + k) * H_ + bn + n];
    }
  }
  __syncthreads();
  {
    const int n = t >> 2, c0 = (t & 3) * 16;
    short tmp[16];
#pragma unroll
    for (int j = 0; j < 16; ++j) tmp[j] = f2bf(T[c0 + j][n]);
    short* dst = Wt + ((size_t)mat * H_ + bn + n) * H_ + bk + c0;
    *(bf16x8*)dst = *(const bf16x8*)tmp;
    *(bf16x8*)(dst + 8) = *(const bf16x8*)(tmp + 8);
  }
}

// ---------------------------------------------------------------------------
// Kernel 2: QKV projection, 128x128 tile, BK=32, register prefetch.
// C = Xb @ Wt^T + b; Q pre-scaled by (1/8)*log2e. grid (32,6,3) block 256.
// 4 waves 2x2, wave tile 64x64 (16 MFMA/step).
// ---------------------------------------------------------------------------
__global__ __launch_bounds__(256) void qkv_gemm_kernel(
    const short* __restrict__ Xb, const short* __restrict__ Wt,
    const float* __restrict__ bq, const float* __restrict__ bk,
    const float* __restrict__ bv, short* __restrict__ QKV) {
  const int mat = blockIdx.z;
  const float* bias = (mat == 0) ? bq : (mat == 1 ? bk : bv);
  const float qsc = (mat == 0) ? 0.125f * LOG2E_ : 1.0f;
  const short* Wm = Wt + (size_t)mat * H_ * H_;
  short* out = QKV + (size_t)mat * M_ * H_;

  __shared__ short Xs[128][72];   // [m][k], pitch 144B (16B-aligned, skewed)
  __shared__ short Ws2[128][72];  // [n][k]

  const int t = threadIdx.x;
  const int w = t >> 6, l = t & 63, c = l & 15, g = l >> 4;
  const int wm = w >> 1, wn = w & 1;
  const int bm = blockIdx.x * 128, bn = blockIdx.y * 128;

  const f32x4 fz = {0.f, 0.f, 0.f, 0.f};
  f32x4 acc[4][4];
#pragma unroll
  for (int i = 0; i < 4; ++i)
#pragma unroll
    for (int j = 0; j < 4; ++j) acc[i][j] = fz;

  bf16x8 xr[2], wr[2];
  // prologue: stage step 0
#pragma unroll
  for (int u = 0; u < 2; ++u) {
    const int i = u * 256 + t;
    xr[u] = *(const bf16x8*)&Xb[(size_t)(bm + (i >> 2)) * H_ + (i & 3) * 8];
    wr[u] = *(const bf16x8*)&Wm[(size_t)(bn + (i >> 2)) * H_ + (i & 3) * 8];
  }
#pragma unroll
  for (int u = 0; u < 2; ++u) {
    const int i = u * 256 + t;
    *(bf16x8*)&Xs[i >> 2][(i & 3) * 8] = xr[u];
    *(bf16x8*)&Ws2[i >> 2][(i & 3) * 8] = wr[u];
  }
  __syncthreads();

  for (int ks = 0; ks < H_ / 32; ++ks) {
    if (ks < H_ / 32 - 1) {  // issue next-step loads early (latency hides under MFMA)
      const int k0 = (ks + 1) * 32;
#pragma unroll
      for (int u = 0; u < 2; ++u) {
        const int i = u * 256 + t;
        xr[u] = *(const bf16x8*)&Xb[(size_t)(bm + (i >> 2)) * H_ + k0 + (i & 3) * 8];
        wr[u] = *(const bf16x8*)&Wm[(size_t)(bn + (i >> 2)) * H_ + k0 + (i & 3) * 8];
      }
    }
    bf16x8 af[4], bfr[4];
#pragma unroll
    for (int mt = 0; mt < 4; ++mt)
      af[mt] = *(const bf16x8*)&Xs[wm * 64 + mt * 16 + c][g * 8];
#pragma unroll
    for (int nt = 0; nt < 4; ++nt)
      bfr[nt] = *(const bf16x8*)&Ws2[wn * 64 + nt * 16 + c][g * 8];
#pragma unroll
    for (int mt = 0; mt < 4; ++mt)
#pragma unroll
      for (int nt = 0; nt < 4; ++nt)
        acc[mt][nt] = MFMA16(af[mt], bfr[nt], acc[mt][nt]);
    __syncthreads();
    if (ks < H_ / 32 - 1) {
#pragma unroll
      for (int u = 0; u < 2; ++u) {
        const int i = u * 256 + t;
        *(bf16x8*)&Xs[i >> 2][(i & 3) * 8] = xr[u];
        *(bf16x8*)&Ws2[i >> 2][(i & 3) * 8] = wr[u];
      }
      __syncthreads();
    }
  }

  // epilogue: bias, scale, scatter to [bh][s][d] bf16
#pragma unroll
  for (int nt = 0; nt < 4; ++nt) {
    const int col = bn + wn * 64 + nt * 16 + c;
    const int h = col >> 6, d = col & 63;
    const float bsc = bias[col] * qsc;
#pragma unroll
    for (int mt = 0; mt < 4; ++mt) {
#pragma unroll
      for (int r = 0; r < 4; ++r) {
        const int row = bm + wm * 64 + mt * 16 + g * 4 + r;
        const int bb = row >> 11, ss = row & (S_ - 1);
        out[((size_t)(bb * NH_ + h) * S_ + ss) * HD_ + d] =
            f2bf(acc[mt][nt][r] * qsc + bsc);
      }
    }
  }
}

// ---------------------------------------------------------------------------
// Kernel 3: V [bh][s][d] -> Vt [bh][d][s]. grid (32,24) block 256.
// ---------------------------------------------------------------------------
__global__ __launch_bounds__(256) void vtrans_kernel(const short* __restrict__ V,
                                                     short* __restrict__ Vt) {
  const int bh = blockIdx.y, s0 = blockIdx.x * 64;
  __shared__ short T[64][72];
  const int t = threadIdx.x;
  {
    const short* src = V + ((size_t)bh * S_ + s0) * HD_;
#pragma unroll
    for (int u = 0; u < 2; ++u) {
      const int i = u * 256 + t;
      *(bf16x8*)&T[i >> 3][(i & 7) * 8] = *(const bf16x8*)&src[i * 8];
    }
  }
  __syncthreads();
  {
    const int d = t >> 2, sc = (t & 3) * 16;
    short tmp[16];
#pragma unroll
    for (int j = 0; j < 16; ++j) tmp[j] = T[sc + j][d];
    short* dst = Vt + ((size_t)bh * HD_ + d) * S_ + s0 + sc;
    *(bf16x8*)dst = *(const bf16x8*)tmp;
    *(bf16x8*)(dst + 8) = *(const bf16x8*)(tmp + 8);
  }
}

// ---------------------------------------------------------------------------
// Kernel 4: flash attention v2 — register-prefetched K/V staging, Q frags
// direct from global (hoisted), exp2 softmax with defer-rescale.
// grid (32,24) block 256 (4 waves x 16 q-rows). KV tile 64.
// ---------------------------------------------------------------------------
__global__ __launch_bounds__(256) void attn_kernel(const short* __restrict__ Q,
                                                   const short* __restrict__ K,
                                                   const short* __restrict__ Vt,
                                                   float* __restrict__ out) {
  __shared__ short Ks[64][72], Vs[64][72];  // pitch 144B
  __shared__ short Ps[4][16][72];           // per-wave P tile

  const int t = threadIdx.x;
  const int w = t >> 6, l = t & 63, c = l & 15, g = l >> 4;
  const int qt = blockIdx.x, bh = blockIdx.y;
  const size_t base = (size_t)bh * S_ * HD_;
  const short* ksrc = K + base;
  const short* vsrc = Vt + (size_t)bh * HD_ * S_;

  bf16x8 kr[2], vr[2];
  // prologue: stage tile 0 (row=i>>3, chunk=i&7 skew -> conflict-free writes)
#pragma unroll
  for (int u = 0; u < 2; ++u) {
    const int i = u * 256 + t;
    kr[u] = *(const bf16x8*)&ksrc[i * 8];
    vr[u] = *(const bf16x8*)&vsrc[(size_t)(i >> 3) * S_ + (i & 7) * 8];
  }
#pragma unroll
  for (int u = 0; u < 2; ++u) {
    const int i = u * 256 + t;
    *(bf16x8*)&Ks[i >> 3][(i & 7) * 8] = kr[u];
    *(bf16x8*)&Vs[i >> 3][(i & 7) * 8] = vr[u];
  }
  __syncthreads();

  // Q fragments: direct global, hoisted out of the K-loop
  const short* qrow = Q + base + (size_t)(qt * 64 + w * 16 + c) * HD_;
  const bf16x8 qa0 = *(const bf16x8*)&qrow[g * 8];
  const bf16x8 qa1 = *(const bf16x8*)&qrow[32 + g * 8];

  const f32x4 fz = {0.f, 0.f, 0.f, 0.f};
  f32x4 ctx[4];
  float m_i[4], l_i[4];
#pragma unroll
  for (int r = 0; r < 4; ++r) { m_i[r] = -INFINITY; l_i[r] = 0.f; ctx[r] = fz; }

  for (int kt = 0; kt < S_ / 64; ++kt) {
    if (kt < S_ / 64 - 1) {  // issue next-tile loads; latency hides under compute
      const short* kn = ksrc + (size_t)(kt + 1) * 64 * HD_;
#pragma unroll
      for (int u = 0; u < 2; ++u) {
        const int i = u * 256 + t;
        kr[u] = *(const bf16x8*)&kn[i * 8];
        vr[u] = *(const bf16x8*)&vsrc[(size_t)(i >> 3) * S_ + (kt + 1) * 64 + (i & 7) * 8];
      }
    }

    // scores (pre-scaled by (1/8)*log2e via Q)
    f32x4 sc[4] = {fz, fz, fz, fz};
#pragma unroll
    for (int nt = 0; nt < 4; ++nt) {
      const bf16x8 kb0 = *(const bf16x8*)&Ks[nt * 16 + c][g * 8];
      const bf16x8 kb1 = *(const bf16x8*)&Ks[nt * 16 + c][32 + g * 8];
      sc[nt] = MFMA16(qa0, kb0, sc[nt]);
      sc[nt] = MFMA16(qa1, kb1, sc[nt]);
    }

    // online softmax (base-2), defer-rescale when the wave's maxes don't grow
#pragma unroll
    for (int r = 0; r < 4; ++r) {
      float mx = fmaxf(fmaxf(sc[0][r], sc[1][r]), fmaxf(sc[2][r], sc[3][r]));
#pragma unroll
      for (int off = 1; off <= 8; off <<= 1) mx = fmaxf(mx, __shfl_xor(mx, off));
      if (__any(mx > m_i[r])) {
        const float mnew = fmaxf(m_i[r], mx);
        const float rs = exp2f(m_i[r] - mnew);
        l_i[r] *= rs;
#pragma unroll
        for (int dt = 0; dt < 4; ++dt) ctx[dt][r] *= rs;
        m_i[r] = mnew;
      }
      const float p0 = exp2f(sc[0][r] - m_i[r]), p1 = exp2f(sc[1][r] - m_i[r]);
      const float p2 = exp2f(sc[2][r] - m_i[r]), p3 = exp2f(sc[3][r] - m_i[r]);
      float ps = p0 + p1 + p2 + p3;
#pragma unroll
      for (int off = 1; off <= 8; off <<= 1) ps += __shfl_xor(ps, off);
      l_i[r] += ps;
      Ps[w][g * 4 + r][c]      = f2bf(p0);
      Ps[w][g * 4 + r][16 + c] = f2bf(p1);
      Ps[w][g * 4 + r][32 + c] = f2bf(p2);
      Ps[w][g * 4 + r][48 + c] = f2bf(p3);
    }

    // PV (Ps wave-private: in-wave lgkm ordering suffices, no barrier)
    {
      const bf16x8 pa0 = *(const bf16x8*)&Ps[w][c][g * 8];
      const bf16x8 pa1 = *(const bf16x8*)&Ps[w][c][32 + g * 8];
#pragma unroll
      for (int dt = 0; dt < 4; ++dt) {
        const bf16x8 vb0 = *(const bf16x8*)&Vs[dt * 16 + c][g * 8];
        const bf16x8 vb1 = *(const bf16x8*)&Vs[dt * 16 + c][32 + g * 8];
        ctx[dt] = MFMA16(pa0, vb0, ctx[dt]);
        ctx[dt] = MFMA16(pa1, vb1, ctx[dt]);
      }
    }
    __syncthreads();  // all waves done reading Ks/Vs
    if (kt < S_ / 64 - 1) {
#pragma unroll
      for (int u = 0; u < 2; ++u) {
        const int i = u * 256 + t;
        *(bf16x8*)&Ks[i >> 3][(i & 7) * 8] = kr[u];
        *(bf16x8*)&Vs[i >> 3][(i & 7) * 8] = vr[u];
      }
      __syncthreads();
    }
  }

  const int bb = bh / NH_, hh = bh % NH_;
#pragma unroll
  for (int r = 0; r < 4; ++r) {
    const float inv = 1.f / l_i[r];
    const int s = qt * 64 + w * 16 + g * 4 + r;
#pragma unroll
    for (int dt = 0; dt < 4; ++dt)
      out[((size_t)bb * S_ + s) * H_ + hh * HD_ + dt * 16 + c] = ctx[dt][r] * inv;
  }
}

// ---------------------------------------------------------------------------
extern "C" void kernel_launch(void* const* d_in, const int* in_sizes, int n_in,
                              void* d_out, int out_size, void* d_ws, size_t ws_size,
                              hipStream_t stream) {
  const float* X  = (const float*)d_in[0];
  const float* Wq = (const float*)d_in[1];
  const float* bq = (const float*)d_in[2];
  const float* Wk = (const float*)d_in[3];
  const float* bk = (const float*)d_in[4];
  const float* Wv = (const float*)d_in[5];
  const float* bv = (const float*)d_in[6];
  float* out = (float*)d_out;

  // ws (bf16 el): QKV[3][24][2048][64] | Vt[24][64][2048] | Wt[3][768][768] | Xb[4096][768]
  short* ws  = (short*)d_ws;
  short* QKV = ws;
  short* Vt  = ws + (size_t)3 * M_ * H_;
  short* Wt  = ws + (size_t)4 * M_ * H_;
  short* Xb  = Wt + (size_t)3 * H_ * H_;
  const short* V = QKV + (size_t)2 * M_ * H_;

  xprep_kernel<<<dim3((M_ * H_) / (256 * 8)), 256, 0, stream>>>(X, Xb);
  wprep_kernel<<<dim3(12, 12, 3), 256, 0, stream>>>(Wq, Wk, Wv, Wt);
  qkv_gemm_kernel<<<dim3(M_ / 128, H_ / 128, 3), 256, 0, stream>>>(Xb, Wt, bq, bk, bv, QKV);
  vtrans_kernel<<<dim3(S_ / 64, BH_), 256, 0, stream>>>(V, Vt);
  attn_kernel<<<dim3(S_ / 64, BH_), 256, 0, stream>>>(QKV, QKV + (size_t)M_ * H_, Vt, out);
}